// Round 5
// baseline (310.638 us; speedup 1.0000x reference)
//
#include <hip/hip_runtime.h>
#include <math.h>

typedef __attribute__((ext_vector_type(8))) short short8;
typedef __attribute__((ext_vector_type(4))) float floatx4;

#define NBLK 256

__device__ __forceinline__ float siluf(float v) { return v / (1.f + expf(-v)); }

// f32 -> bf16 bits, round-to-nearest-even
__device__ __forceinline__ short f2bf(float f) {
    unsigned u = __float_as_uint(f);
    u += 0x7fffu + ((u >> 16) & 1u);
    return (short)(u >> 16);
}

__global__ void init_kernel(int* bar) {
    if (threadIdx.x < 16) bar[threadIdx.x] = 0;
}

// Device-scope grid barrier: per-barrier counter cell (no reset mid-kernel; init kernel zeroes).
__device__ __forceinline__ void gbar(int* bar, int i) {
    __syncthreads();
    if (threadIdx.x == 0) {
        __threadfence();  // release: flush this XCD's L2 writes
        int old = __hip_atomic_fetch_add(&bar[i], 1, __ATOMIC_ACQ_REL, __HIP_MEMORY_SCOPE_AGENT);
        if (old != NBLK - 1) {
            while (__hip_atomic_load(&bar[i], __ATOMIC_RELAXED, __HIP_MEMORY_SCOPE_AGENT) < NBLK)
                __builtin_amdgcn_s_sleep(1);
        }
        __threadfence();  // acquire: invalidate stale L1/L2 lines
    }
    __syncthreads();
}

// ---- A-fragment loaders ----
// MODE 0: bf16 A (lda in shorts)
// MODE 1: e1-fused: A = xz slices (NSUM=2, stride ss); u = silu((s0+s1)*aux0[j]+aux1[j])
// MODE 2: sum NSUM f32 slices
// MODE 3: sum NSUM slices + aux0[j] + aux1[r*lda+j]
template<int MODE, int NSUM>
__device__ __forceinline__ short8 a_frag(const void* __restrict__ A, int lda, size_t ss,
                                         int r, int j0,
                                         const float* __restrict__ aux0,
                                         const float* __restrict__ aux1) {
    if constexpr (MODE == 0) {
        return *(const short8*)((const short*)A + (size_t)r * lda + j0);
    } else {
        const float* Af = (const float*)A;
        size_t base = (size_t)r * lda + j0;
        float v[8];
#pragma unroll
        for (int i = 0; i < 8; ++i) {
            float t;
            if constexpr (MODE == 1) {
                t = Af[base + i] + Af[ss + base + i];
                t = siluf(t * aux0[j0 + i] + aux1[j0 + i]);
            } else {
                t = 0.f;
#pragma unroll
                for (int s = 0; s < NSUM; ++s) t += Af[(size_t)s * ss + base + i];
                if constexpr (MODE == 3) t += aux0[j0 + i] + aux1[base + i];
            }
            v[i] = t;
        }
        short8 sv;
#pragma unroll
        for (int i = 0; i < 8; ++i) sv[i] = f2bf(v[i]);
        return sv;
    }
}

// ---- one GEMM tile-task: M=128 (4 waves x 32 rows), 64 cols at n0, kSteps x 32 K ----
template<int MODE, int NSUM>
__device__ __forceinline__ void gemm_stage(const void* __restrict__ A, int lda, size_t ss,
                                           const float* __restrict__ aux0,
                                           const float* __restrict__ aux1,
                                           const float* __restrict__ B, int ldb,
                                           float* __restrict__ Cs, int ldc,
                                           int n0, int k0, int kSteps) {
    const int tid = threadIdx.x;
    const int w = tid >> 6;
    const int l = tid & 63;
    const int lane15 = l & 15;
    const int lgrp = l >> 4;
    const int r0 = w * 32 + lane15;
    const float* Bp = B + (size_t)(k0 + lgrp * 8) * ldb + n0 + lane15;

    floatx4 acc[2][4];
#pragma unroll
    for (int i = 0; i < 2; ++i)
#pragma unroll
        for (int j = 0; j < 4; ++j) acc[i][j] = (floatx4)0.f;

    for (int s = 0; s < kSteps; ++s) {
        int j0 = k0 + s * 32 + lgrp * 8;
        short8 a0 = a_frag<MODE, NSUM>(A, lda, ss, r0, j0, aux0, aux1);
        short8 a1 = a_frag<MODE, NSUM>(A, lda, ss, r0 + 16, j0, aux0, aux1);
        float bv[4][8];
#pragma unroll
        for (int i = 0; i < 8; ++i) {
            const float* Br = Bp + (size_t)i * ldb;
#pragma unroll
            for (int nt = 0; nt < 4; ++nt) bv[nt][i] = Br[nt * 16];
        }
        Bp += 32 * (size_t)ldb;
        short8 vb[4];
#pragma unroll
        for (int nt = 0; nt < 4; ++nt)
#pragma unroll
            for (int i = 0; i < 8; ++i) vb[nt][i] = f2bf(bv[nt][i]);
#pragma unroll
        for (int nt = 0; nt < 4; ++nt) {
            acc[0][nt] = __builtin_amdgcn_mfma_f32_16x16x32_bf16(a0, vb[nt], acc[0][nt], 0, 0, 0);
            acc[1][nt] = __builtin_amdgcn_mfma_f32_16x16x32_bf16(a1, vb[nt], acc[1][nt], 0, 0, 0);
        }
    }
    const int rbase = w * 32 + lgrp * 4;
#pragma unroll
    for (int mf = 0; mf < 2; ++mf)
#pragma unroll
        for (int nt = 0; nt < 4; ++nt)
#pragma unroll
            for (int r = 0; r < 4; ++r)
                Cs[(size_t)(rbase + mf * 16 + r) * ldc + n0 + nt * 16 + lane15] = acc[mf][nt][r];
}

// ---------------- the persistent uber-kernel ----------------
__global__ __launch_bounds__(256, 2) void uber_kernel(
        const float* __restrict__ x, const float* __restrict__ c,
        const float* __restrict__ ln_g, const float* __restrict__ ln_b,
        const float* __restrict__ W_in, const float* __restrict__ cw3,
        const float* __restrict__ cb, const float* __restrict__ W_x,
        const float* __restrict__ W_dt, const float* __restrict__ b_dt,
        const float* __restrict__ Dv, const float* __restrict__ W_out,
        const float* __restrict__ b_out, const float* __restrict__ W_d,
        const float* __restrict__ b_d, const float* __restrict__ W_f,
        const float* __restrict__ b_f, const float* __restrict__ W_o,
        const float* __restrict__ b_o, float* __restrict__ out,
        int* __restrict__ bar,
        short* __restrict__ h_bf, short* __restrict__ c_bf,
        float* __restrict__ xz_p, float* __restrict__ gb_p,
        float* __restrict__ xdbl_p, float* __restrict__ dacc_p,
        short* __restrict__ y_bf, float* __restrict__ mo_p,
        float* __restrict__ zd_p, short* __restrict__ z_bf,
        float* __restrict__ out_p) {
    const int bid = blockIdx.x;
    const int tid = threadIdx.x;
    __shared__ float sdata[256];

    const size_t XZ_SL = (size_t)128 * 4096;
    const size_t GB_SL = (size_t)128 * 1024;
    const size_t XD_SL = (size_t)128 * 1536;
    const size_t DA_SL = (size_t)128 * 2048;
    const size_t MO_SL = (size_t)128 * 1024;
    const size_t ZD_SL = (size_t)128 * 512;
    const size_t OU_SL = (size_t)128 * 1024;

    // ---- S0: LayerNorm rows (blocks 0..127) / c -> bf16 (blocks 128..255) ----
    if (bid < 128) {
        int b = bid;
        const float* xr = x + b * 1024;
        float v[4];
        float s = 0.f;
#pragma unroll
        for (int i = 0; i < 4; ++i) { v[i] = xr[tid + i * 256]; s += v[i]; }
        sdata[tid] = s; __syncthreads();
        for (int st = 128; st > 0; st >>= 1) { if (tid < st) sdata[tid] += sdata[tid + st]; __syncthreads(); }
        float mu = sdata[0] * (1.f / 1024.f);
        __syncthreads();
        float s2 = 0.f;
#pragma unroll
        for (int i = 0; i < 4; ++i) { float d = v[i] - mu; s2 += d * d; }
        sdata[tid] = s2; __syncthreads();
        for (int st = 128; st > 0; st >>= 1) { if (tid < st) sdata[tid] += sdata[tid + st]; __syncthreads(); }
        float inv = rsqrtf(sdata[0] * (1.f / 1024.f) + 1e-5f);
        short* hr = h_bf + b * 1024;
#pragma unroll
        for (int i = 0; i < 4; ++i) {
            int j = tid + i * 256;
            hr[j] = f2bf((v[i] - mu) * inv * ln_g[j] + ln_b[j]);
        }
    } else {
        int b = bid - 128;
        const float* cr = c + b * 512;
        short* cbr = c_bf + b * 512;
        cbr[tid] = f2bf(cr[tid]);
        cbr[tid + 256] = f2bf(cr[tid + 256]);
    }
    gbar(bar, 0);

    // ---- S1: G1 (h @ W_in -> xz, 64nb x 2ks, chunk 512) + G6 (c @ W_f -> gb, 16nb x 8ks, chunk 64) ----
    if (bid < 128) {
        int nb = bid >> 1, ks = bid & 1;
        gemm_stage<0, 0>(h_bf, 1024, 0, nullptr, nullptr, W_in, 4096,
                         xz_p + (size_t)ks * XZ_SL, 4096, nb * 64, ks * 512, 16);
    } else {
        int t = bid - 128;
        int nb = t >> 3, ks = t & 7;
        gemm_stage<0, 0>(c_bf, 512, 0, nullptr, nullptr, W_f, 1024,
                         gb_p + (size_t)ks * GB_SL, 1024, nb * 64, ks * 64, 2);
    }
    gbar(bar, 1);

    // ---- S2: G2 (u @ W_x -> xdbl, 24nb x 8ks, chunk 256) with e1-fused loader ----
    if (bid < 192) {
        int nb = bid >> 3, ks = bid & 7;
        gemm_stage<1, 2>(xz_p, 4096, XZ_SL, cw3, cb, W_x, 1536,
                         xdbl_p + (size_t)ks * XD_SL, 1536, nb * 64, ks * 256, 8);
    }
    gbar(bar, 2);

    // ---- S3: G3 (dr @ W_dt -> dacc, 32nb x 8ks, chunk 64) with sum-8 loader ----
    {
        int nb = bid >> 3, ks = bid & 7;
        gemm_stage<2, 8>(xdbl_p, 1536, XD_SL, nullptr, nullptr, W_dt, 2048,
                         dacc_p + (size_t)ks * DA_SL, 2048, nb * 64, ks * 64, 2);
    }
    gbar(bar, 3);

    // ---- S4: e3 (svec inline; u/sres recomputed from xz) -> y_bf ; 2 blocks/row ----
    {
        int row = bid >> 1, half = bid & 1;
        // svec = dot(Bm, Cm) for this row (redundant across the 2 blocks of the row)
        float s = 0.f;
#pragma unroll
        for (int q = 0; q < 2; ++q) {
            int n = tid + q * 256;
            float bm = 0.f, cm = 0.f;
#pragma unroll
            for (int sl = 0; sl < 8; ++sl) {
                bm += xdbl_p[(size_t)sl * XD_SL + (size_t)row * 1536 + 512 + n];
                cm += xdbl_p[(size_t)sl * XD_SL + (size_t)row * 1536 + 1024 + n];
            }
            s += bm * cm;
        }
        sdata[tid] = s; __syncthreads();
        for (int st = 128; st > 0; st >>= 1) { if (tid < st) sdata[tid] += sdata[tid + st]; __syncthreads(); }
        float svec = sdata[0];
        __syncthreads();
#pragma unroll
        for (int kk = 0; kk < 4; ++kk) {
            int j = half * 1024 + tid + kk * 256;
            float t = b_dt[j];
#pragma unroll
            for (int sl = 0; sl < 8; ++sl) t += dacc_p[(size_t)sl * DA_SL + (size_t)row * 2048 + j];
            float delta = fmaxf(t, 0.f) + log1pf(expf(-fabsf(t)));
            float xv = xz_p[(size_t)row * 4096 + j] + xz_p[XZ_SL + (size_t)row * 4096 + j];
            float u = siluf(xv * cw3[j] + cb[j]);
            float rv = xz_p[(size_t)row * 4096 + 2048 + j] + xz_p[XZ_SL + (size_t)row * 4096 + 2048 + j];
            float sr = siluf(rv);
            y_bf[(size_t)row * 2048 + j] = f2bf(u * (delta * svec + Dv[j]) * sr);
        }
    }
    gbar(bar, 4);

    // ---- S5: G4 (y @ W_out -> mo, 16nb x 8ks, chunk 256) ----
    if (bid < 128) {
        int nb = bid >> 3, ks = bid & 7;
        gemm_stage<0, 0>(y_bf, 2048, 0, nullptr, nullptr, W_out, 1024,
                         mo_p + (size_t)ks * MO_SL, 1024, nb * 64, ks * 256, 8);
    }
    gbar(bar, 5);

    // ---- S6: G5 ((sum mo + b_out + x) @ W_d -> zd, 8nb x 16ks, chunk 64) ----
    if (bid < 128) {
        int nb = bid >> 4, ks = bid & 15;
        gemm_stage<3, 8>(mo_p, 1024, MO_SL, b_out, x, W_d, 512,
                         zd_p + (size_t)ks * ZD_SL, 512, nb * 64, ks * 64, 2);
    }
    gbar(bar, 6);

    // ---- S7: e5 (FiLM(gelu(sum zd + b_d))) -> z_bf ----
    {
        int idx = bid * 256 + tid;   // 128*512
        int row = idx >> 9, n = idx & 511;
        float t = b_d[n];
#pragma unroll
        for (int sl = 0; sl < 16; ++sl) t += zd_p[(size_t)sl * ZD_SL + idx];
        float zg = 0.5f * t * (1.f + erff(t * 0.70710678118654752f));
        float gq = b_f[n], bb = b_f[512 + n];
#pragma unroll
        for (int sl = 0; sl < 8; ++sl) {
            gq += gb_p[(size_t)sl * GB_SL + (size_t)row * 1024 + n];
            bb += gb_p[(size_t)sl * GB_SL + (size_t)row * 1024 + 512 + n];
        }
        z_bf[idx] = f2bf(zg * gq + bb);
    }
    gbar(bar, 7);

    // ---- S8: G7 (z @ W_o -> out_p, 16nb x 16ks, chunk 32) ----
    {
        int nb = bid >> 4, ks = bid & 15;
        gemm_stage<0, 0>(z_bf, 512, 0, nullptr, nullptr, W_o, 1024,
                         out_p + (size_t)ks * OU_SL, 1024, nb * 64, ks * 32, 1);
    }
    gbar(bar, 8);

    // ---- S9: e6 (sum 16 out slices + b_o) -> out ----
#pragma unroll
    for (int q = 0; q < 2; ++q) {
        int idx = bid * 512 + q * 256 + tid;  // 128*1024
        int j = idx & 1023;
        float t = b_o[j];
#pragma unroll
        for (int sl = 0; sl < 16; ++sl) t += out_p[(size_t)sl * OU_SL + idx];
        out[idx] = t;
    }
}

extern "C" void kernel_launch(void* const* d_in, const int* in_sizes, int n_in,
                              void* d_out, int out_size, void* d_ws, size_t ws_size,
                              hipStream_t stream) {
    (void)in_sizes; (void)n_in; (void)out_size; (void)ws_size;
    const float* x     = (const float*)d_in[0];
    const float* c     = (const float*)d_in[1];
    const float* ln_g  = (const float*)d_in[2];
    const float* ln_b  = (const float*)d_in[3];
    const float* W_in  = (const float*)d_in[4];
    const float* convw = (const float*)d_in[5];
    const float* convb = (const float*)d_in[6];
    const float* W_x   = (const float*)d_in[7];
    const float* W_dt  = (const float*)d_in[8];
    const float* b_dt  = (const float*)d_in[9];
    // d_in[10] = A_log: provably unused (scan length 1 from h0 = 0)
    const float* Dv    = (const float*)d_in[11];
    const float* W_out = (const float*)d_in[12];
    const float* b_out = (const float*)d_in[13];
    const float* W_d   = (const float*)d_in[14];
    const float* b_d   = (const float*)d_in[15];
    const float* W_f   = (const float*)d_in[16];
    const float* b_f   = (const float*)d_in[17];
    const float* W_o   = (const float*)d_in[18];
    const float* b_o   = (const float*)d_in[19];
    float* out = (float*)d_out;

    char* ws = (char*)d_ws;
    size_t off = 0;
    auto alloc = [&](size_t bytes) { void* p = ws + off; off += (bytes + 255) & ~(size_t)255; return p; };
    int*   bar    = (int*)  alloc(16 * sizeof(int));
    short* h_bf   = (short*)alloc(128 * 1024 * 2);
    short* c_bf   = (short*)alloc(128 * 512 * 2);
    float* xz_p   = (float*)alloc((size_t)2 * 128 * 4096 * 4);
    float* gb_p   = (float*)alloc((size_t)8 * 128 * 1024 * 4);
    float* xdbl_p = (float*)alloc((size_t)8 * 128 * 1536 * 4);
    float* dacc_p = (float*)alloc((size_t)8 * 128 * 2048 * 4);
    short* y_bf   = (short*)alloc(128 * 2048 * 2);
    float* mo_p   = (float*)alloc((size_t)8 * 128 * 1024 * 4);
    float* zd_p   = (float*)alloc((size_t)16 * 128 * 512 * 4);
    short* z_bf   = (short*)alloc(128 * 512 * 2);
    float* out_p  = (float*)alloc((size_t)16 * 128 * 1024 * 4);

    init_kernel<<<1, 64, 0, stream>>>(bar);
    uber_kernel<<<NBLK, 256, 0, stream>>>(
        x, c, ln_g, ln_b, W_in, convw + 3 * 2048, convb, W_x, W_dt, b_dt,
        Dv, W_out, b_out, W_d, b_d, W_f, b_f, W_o, b_o, out,
        bar, h_bf, c_bf, xz_p, gb_p, xdbl_p, dacc_p, y_bf, mo_p, zd_p, z_bf, out_p);
}

// Round 6
// 143.048 us; speedup vs baseline: 2.1716x; 2.1716x over previous
//
#include <hip/hip_runtime.h>
#include <math.h>

typedef __attribute__((ext_vector_type(8))) short short8;
typedef __attribute__((ext_vector_type(4))) float floatx4;

__device__ __forceinline__ float siluf(float v) { return v / (1.f + expf(-v)); }

// f32 -> bf16 bits, round-to-nearest-even
__device__ __forceinline__ short f2bf(float f) {
    unsigned u = __float_as_uint(f);
    u += 0x7fffu + ((u >> 16) & 1u);
    return (short)(u >> 16);
}

// ---------------- LayerNorm (1024) -> bf16 h ; also convert c -> bf16 ----------------
__global__ __launch_bounds__(256) void ln_cvt_kernel(const float* __restrict__ x,
                                                     const float* __restrict__ g,
                                                     const float* __restrict__ be,
                                                     const float* __restrict__ c,
                                                     short* __restrict__ h_bf,
                                                     short* __restrict__ c_bf) {
    int b = blockIdx.x;
    int tid = threadIdx.x;
    __shared__ float sdata[256];
    const float* xr = x + b * 1024;
    float v[4];
    float s = 0.f;
#pragma unroll
    for (int i = 0; i < 4; ++i) { v[i] = xr[tid + i * 256]; s += v[i]; }
    sdata[tid] = s; __syncthreads();
    for (int st = 128; st > 0; st >>= 1) { if (tid < st) sdata[tid] += sdata[tid + st]; __syncthreads(); }
    float mu = sdata[0] * (1.f / 1024.f);
    __syncthreads();
    float s2 = 0.f;
#pragma unroll
    for (int i = 0; i < 4; ++i) { float d = v[i] - mu; s2 += d * d; }
    sdata[tid] = s2; __syncthreads();
    for (int st = 128; st > 0; st >>= 1) { if (tid < st) sdata[tid] += sdata[tid + st]; __syncthreads(); }
    float inv = rsqrtf(sdata[0] * (1.f / 1024.f) + 1e-5f);
    short* hr = h_bf + b * 1024;
#pragma unroll
    for (int i = 0; i < 4; ++i) {
        int j = tid + i * 256;
        hr[j] = f2bf((v[i] - mu) * inv * g[j] + be[j]);
    }
    const float* cr = c + b * 512;
    short* cbr = c_bf + b * 512;
    cbr[tid] = f2bf(cr[tid]);
    cbr[tid + 256] = f2bf(cr[tid + 256]);
}

// ---------------- full-K GEMM core: M=128 (8 waves x 16 rows), BN=32 (2 x 16-col frags) ----------------
// Depth-2 register prefetch pipeline; no LDS, no barriers, no atomics.
// acc[nt][r] -> C[rbase + r][n0 + nt*16 + lane15], rbase = (tid>>6)*16 + ((tid&63)>>4)*4
template<int KSTEPS>
__device__ __forceinline__ void gemm32(const short* __restrict__ A, int lda,
                                       const float* __restrict__ B, int ldb,
                                       int n0, floatx4 acc[2]) {
    const int tid = threadIdx.x;
    const int w = tid >> 6;
    const int l = tid & 63;
    const int lane15 = l & 15;
    const int lgrp = l >> 4;
    const int r0 = w * 16 + lane15;
    const short* Ap = A + (size_t)r0 * lda + lgrp * 8;
    const float* Bp = B + (size_t)(lgrp * 8) * ldb + n0 + lane15;
    acc[0] = (floatx4)0.f;
    acc[1] = (floatx4)0.f;

    short8 a_cur = *(const short8*)Ap; Ap += 32;
    float bv_cur[2][8];
#pragma unroll
    for (int i = 0; i < 8; ++i) {
        const float* Br = Bp + (size_t)i * ldb;
        bv_cur[0][i] = Br[0];
        bv_cur[1][i] = Br[16];
    }
    Bp += 32 * (size_t)ldb;

#pragma unroll
    for (int s = 0; s < KSTEPS; ++s) {
        short8 a_nxt;
        float bv_nxt[2][8];
        if (s + 1 < KSTEPS) {
            a_nxt = *(const short8*)Ap; Ap += 32;
#pragma unroll
            for (int i = 0; i < 8; ++i) {
                const float* Br = Bp + (size_t)i * ldb;
                bv_nxt[0][i] = Br[0];
                bv_nxt[1][i] = Br[16];
            }
            Bp += 32 * (size_t)ldb;
        }
        short8 vb0, vb1;
#pragma unroll
        for (int i = 0; i < 8; ++i) { vb0[i] = f2bf(bv_cur[0][i]); vb1[i] = f2bf(bv_cur[1][i]); }
        acc[0] = __builtin_amdgcn_mfma_f32_16x16x32_bf16(a_cur, vb0, acc[0], 0, 0, 0);
        acc[1] = __builtin_amdgcn_mfma_f32_16x16x32_bf16(a_cur, vb1, acc[1], 0, 0, 0);
        a_cur = a_nxt;
#pragma unroll
        for (int i = 0; i < 8; ++i) { bv_cur[0][i] = bv_nxt[0][i]; bv_cur[1][i] = bv_nxt[1][i]; }
    }
}

#define EPI_SETUP \
    const int tid = threadIdx.x; \
    const int lane15 = tid & 15; \
    const int rbase = (tid >> 6) * 16 + ((tid & 63) >> 4) * 4;

// ---- G1 (+e1) and G6 combined: blocks 0..127 -> G1 tile; 128..159 -> G6 tile ----
__global__ __launch_bounds__(512) void g1g6_kernel(const short* __restrict__ h_bf,
                                                   const float* __restrict__ W_in,
                                                   const short* __restrict__ c_bf,
                                                   const float* __restrict__ W_f,
                                                   const float* __restrict__ cw3,
                                                   const float* __restrict__ cb,
                                                   float* __restrict__ u_f32,
                                                   short* __restrict__ u_bf,
                                                   float* __restrict__ sres,
                                                   float* __restrict__ gb) {
    EPI_SETUP
    floatx4 acc[2];
    if (blockIdx.x < 128) {
        int n0 = blockIdx.x * 32;
        gemm32<32>(h_bf, 1024, W_in, 4096, n0, acc);
#pragma unroll
        for (int nt = 0; nt < 2; ++nt) {
            int col = n0 + nt * 16 + lane15;
#pragma unroll
            for (int r = 0; r < 4; ++r) {
                int row = rbase + r;
                float val = acc[nt][r];
                if (col < 2048) {
                    float u = siluf(val * cw3[col] + cb[col]);
                    u_f32[(size_t)row * 2048 + col] = u;
                    u_bf[(size_t)row * 2048 + col] = f2bf(u);
                } else {
                    sres[(size_t)row * 2048 + col - 2048] = siluf(val);
                }
            }
        }
    } else {
        int n0 = (blockIdx.x - 128) * 32;
        gemm32<16>(c_bf, 512, W_f, 1024, n0, acc);
#pragma unroll
        for (int nt = 0; nt < 2; ++nt) {
            int col = n0 + nt * 16 + lane15;
#pragma unroll
            for (int r = 0; r < 4; ++r)
                gb[(size_t)(rbase + r) * 1024 + col] = acc[nt][r];
        }
    }
}

// ---- G2: u_bf @ W_x (2048 x 1536); cols<512 -> dr_bf, cols>=512 -> bc (Bm|Cm) ----
__global__ __launch_bounds__(512) void g2_kernel(const short* __restrict__ u_bf,
                                                 const float* __restrict__ W_x,
                                                 short* __restrict__ dr_bf,
                                                 float* __restrict__ bc) {
    EPI_SETUP
    floatx4 acc[2];
    int n0 = blockIdx.x * 32;
    gemm32<64>(u_bf, 2048, W_x, 1536, n0, acc);
#pragma unroll
    for (int nt = 0; nt < 2; ++nt) {
        int col = n0 + nt * 16 + lane15;
#pragma unroll
        for (int r = 0; r < 4; ++r) {
            int row = rbase + r;
            float val = acc[nt][r];
            if (col < 512) dr_bf[(size_t)row * 512 + col] = f2bf(val);
            else           bc[(size_t)row * 1024 + col - 512] = val;
        }
    }
}

// ---- svec[b] = dot(Bm[b], Cm[b]) ----
__global__ __launch_bounds__(256) void svec_kernel(const float* __restrict__ bc,
                                                   float* __restrict__ svec) {
    int b = blockIdx.x;
    int tid = threadIdx.x;
    __shared__ float sdata[256];
    const float* row = bc + (size_t)b * 1024;
    float s = row[tid] * row[512 + tid];
    int t2 = tid + 256;
    if (t2 < 512) {}  // tid in [0,256): handle both halves explicitly
    s += row[tid + 256] * row[768 + tid];
    sdata[tid] = s; __syncthreads();
    for (int st = 128; st > 0; st >>= 1) { if (tid < st) sdata[tid] += sdata[tid + st]; __syncthreads(); }
    if (tid == 0) svec[b] = sdata[0];
}

// ---- G3 (+e3): dr_bf @ W_dt (512 x 2048); y = u*(softplus(val+b_dt)*svec+D)*sres -> bf16 ----
__global__ __launch_bounds__(512) void g3_kernel(const short* __restrict__ dr_bf,
                                                 const float* __restrict__ W_dt,
                                                 const float* __restrict__ b_dt,
                                                 const float* __restrict__ svec,
                                                 const float* __restrict__ Dv,
                                                 const float* __restrict__ u_f32,
                                                 const float* __restrict__ sres,
                                                 short* __restrict__ y_bf) {
    EPI_SETUP
    floatx4 acc[2];
    int n0 = blockIdx.x * 32;
    gemm32<16>(dr_bf, 512, W_dt, 2048, n0, acc);
#pragma unroll
    for (int nt = 0; nt < 2; ++nt) {
        int col = n0 + nt * 16 + lane15;
#pragma unroll
        for (int r = 0; r < 4; ++r) {
            int row = rbase + r;
            float t = acc[nt][r] + b_dt[col];
            float delta = fmaxf(t, 0.f) + log1pf(expf(-fabsf(t)));  // stable softplus
            size_t idx = (size_t)row * 2048 + col;
            y_bf[idx] = f2bf(u_f32[idx] * (delta * svec[row] + Dv[col]) * sres[idx]);
        }
    }
}

// ---- G4 (+e4): y_bf @ W_out (2048 x 1024); mamba = val + b_out + x -> bf16 ----
__global__ __launch_bounds__(512) void g4_kernel(const short* __restrict__ y_bf,
                                                 const float* __restrict__ W_out,
                                                 const float* __restrict__ b_out,
                                                 const float* __restrict__ x,
                                                 short* __restrict__ mamba_bf) {
    EPI_SETUP
    floatx4 acc[2];
    int n0 = blockIdx.x * 32;
    gemm32<64>(y_bf, 2048, W_out, 1024, n0, acc);
#pragma unroll
    for (int nt = 0; nt < 2; ++nt) {
        int col = n0 + nt * 16 + lane15;
#pragma unroll
        for (int r = 0; r < 4; ++r) {
            int row = rbase + r;
            size_t idx = (size_t)row * 1024 + col;
            mamba_bf[idx] = f2bf(acc[nt][r] + b_out[col] + x[idx]);
        }
    }
}

// ---- G5 (+e5): mamba_bf @ W_d (1024 x 512); z = gelu(val+b_d)*(gb+b_f) FiLM -> bf16 ----
__global__ __launch_bounds__(512) void g5_kernel(const short* __restrict__ mamba_bf,
                                                 const float* __restrict__ W_d,
                                                 const float* __restrict__ b_d,
                                                 const float* __restrict__ gb,
                                                 const float* __restrict__ b_f,
                                                 short* __restrict__ z_bf) {
    EPI_SETUP
    floatx4 acc[2];
    int n0 = blockIdx.x * 32;
    gemm32<32>(mamba_bf, 1024, W_d, 512, n0, acc);
#pragma unroll
    for (int nt = 0; nt < 2; ++nt) {
        int col = n0 + nt * 16 + lane15;
#pragma unroll
        for (int r = 0; r < 4; ++r) {
            int row = rbase + r;
            float t = acc[nt][r] + b_d[col];
            float zg = 0.5f * t * (1.f + erff(t * 0.70710678118654752f));
            float gq = gb[(size_t)row * 1024 + col] + b_f[col];
            float bb = gb[(size_t)row * 1024 + 512 + col] + b_f[512 + col];
            z_bf[(size_t)row * 512 + col] = f2bf(zg * gq + bb);
        }
    }
}

// ---- G7 (+e6): z_bf @ W_o (512 x 1024); out = val + b_o ----
__global__ __launch_bounds__(512) void g7_kernel(const short* __restrict__ z_bf,
                                                 const float* __restrict__ W_o,
                                                 const float* __restrict__ b_o,
                                                 float* __restrict__ out) {
    EPI_SETUP
    floatx4 acc[2];
    int n0 = blockIdx.x * 32;
    gemm32<16>(z_bf, 512, W_o, 1024, n0, acc);
#pragma unroll
    for (int nt = 0; nt < 2; ++nt) {
        int col = n0 + nt * 16 + lane15;
#pragma unroll
        for (int r = 0; r < 4; ++r)
            out[(size_t)(rbase + r) * 1024 + col] = acc[nt][r] + b_o[col];
    }
}

extern "C" void kernel_launch(void* const* d_in, const int* in_sizes, int n_in,
                              void* d_out, int out_size, void* d_ws, size_t ws_size,
                              hipStream_t stream) {
    (void)in_sizes; (void)n_in; (void)out_size; (void)ws_size;
    const float* x     = (const float*)d_in[0];
    const float* c     = (const float*)d_in[1];
    const float* ln_g  = (const float*)d_in[2];
    const float* ln_b  = (const float*)d_in[3];
    const float* W_in  = (const float*)d_in[4];
    const float* convw = (const float*)d_in[5];
    const float* convb = (const float*)d_in[6];
    const float* W_x   = (const float*)d_in[7];
    const float* W_dt  = (const float*)d_in[8];
    const float* b_dt  = (const float*)d_in[9];
    // d_in[10] = A_log: provably unused (scan length 1 from h0 = 0)
    const float* Dv    = (const float*)d_in[11];
    const float* W_out = (const float*)d_in[12];
    const float* b_out = (const float*)d_in[13];
    const float* W_d   = (const float*)d_in[14];
    const float* b_d   = (const float*)d_in[15];
    const float* W_f   = (const float*)d_in[16];
    const float* b_f   = (const float*)d_in[17];
    const float* W_o   = (const float*)d_in[18];
    const float* b_o   = (const float*)d_in[19];
    float* out = (float*)d_out;

    char* ws = (char*)d_ws;
    size_t off = 0;
    auto alloc = [&](size_t bytes) { void* p = ws + off; off += (bytes + 255) & ~(size_t)255; return p; };
    short* h_bf     = (short*)alloc(128 * 1024 * 2);
    short* c_bf     = (short*)alloc(128 * 512 * 2);
    float* u_f32    = (float*)alloc((size_t)128 * 2048 * 4);
    short* u_bf     = (short*)alloc(128 * 2048 * 2);
    float* sres     = (float*)alloc((size_t)128 * 2048 * 4);
    float* gb       = (float*)alloc((size_t)128 * 1024 * 4);
    short* dr_bf    = (short*)alloc(128 * 512 * 2);
    float* bc       = (float*)alloc((size_t)128 * 1024 * 4);
    float* svec     = (float*)alloc(128 * 4);
    short* y_bf     = (short*)alloc(128 * 2048 * 2);
    short* mamba_bf = (short*)alloc(128 * 1024 * 2);
    short* z_bf     = (short*)alloc(128 * 512 * 2);

    // 1) LayerNorm + c->bf16
    ln_cvt_kernel<<<128, 256, 0, stream>>>(x, ln_g, ln_b, c, h_bf, c_bf);
    // 2) G1 (+e1 fused) || G6
    g1g6_kernel<<<160, 512, 0, stream>>>(h_bf, W_in, c_bf, W_f, convw + 3 * 2048, convb,
                                         u_f32, u_bf, sres, gb);
    // 3) G2 (dr_bf + bc)
    g2_kernel<<<48, 512, 0, stream>>>(u_bf, W_x, dr_bf, bc);
    // 4) svec
    svec_kernel<<<128, 256, 0, stream>>>(bc, svec);
    // 5) G3 (+e3 fused)
    g3_kernel<<<64, 512, 0, stream>>>(dr_bf, W_dt, b_dt, svec, Dv, u_f32, sres, y_bf);
    // 6) G4 (+e4 fused)
    g4_kernel<<<32, 512, 0, stream>>>(y_bf, W_out, b_out, x, mamba_bf);
    // 7) G5 (+e5 fused)
    g5_kernel<<<16, 512, 0, stream>>>(mamba_bf, W_d, b_d, gb, b_f, z_bf);
    // 8) G7 (+e6 fused)
    g7_kernel<<<32, 512, 0, stream>>>(z_bf, W_o, b_o, out);
}